// Round 8
// baseline (291.099 us; speedup 1.0000x reference)
//
#include <hip/hip_runtime.h>
#include <math.h>

#define N_TOT 8192
#define N_SRC 4096
#define D_DIM 512
#define BM 128
#define NT (N_TOT / BM)            /* 64 tiles per dim */
#define NTILES (NT * (NT + 1) / 2) /* 2080 triangular tiles; 2080 % 8 == 0 */
#define NPREP 256                  /* k_prep blocks, 32 rows each */

typedef short bf16x8 __attribute__((ext_vector_type(8)));
typedef unsigned short u16x8 __attribute__((ext_vector_type(8)));
typedef float f32x4 __attribute__((ext_vector_type(4)));

// ws layout (bytes):
//   0      : double accum[4]   {2=loss}
//   64     : unsigned int cnt
//   128    : float invbw[5]
//   4096   : float sq[8192]             (32 KB)
//   36864  : float w[4096]              (16 KB)
//   53248  : float colpart[256][512]    (512 KB)
//   577536 : ushort xhi[8192*512]       (8 MB)

__device__ __forceinline__ unsigned short f2bf_rn(float v) {
    unsigned int u = __float_as_uint(v);
    unsigned int r = (u + 0x7FFFu + ((u >> 16) & 1u)) >> 16;
    return (unsigned short)r;
}

// One pass over x: bf16 round + row sum-of-squares + column-sum partials.
// 256 blocks x 32 rows; wave per 8 rows; lane owns cols lane*8..+7.
__global__ __launch_bounds__(256) void k_prep(const float* __restrict__ x,
                                              unsigned short* __restrict__ xhi,
                                              float* __restrict__ sq,
                                              float* __restrict__ colpart) {
    const int wave = threadIdx.x >> 6;
    const int lane = threadIdx.x & 63;
    __shared__ float colbuf[4][512];
    float fcol[8];
#pragma unroll
    for (int j = 0; j < 8; ++j) fcol[j] = 0.f;

#pragma unroll
    for (int r8 = 0; r8 < 8; ++r8) {
        const int row = blockIdx.x * 32 + wave * 8 + r8;
        const size_t base = (size_t)row * D_DIM + lane * 8;
        float v[8];
        *(float4*)&v[0] = *(const float4*)(x + base);
        *(float4*)&v[4] = *(const float4*)(x + base + 4);
        u16x8 h;
        float s = 0.f;
#pragma unroll
        for (int j = 0; j < 8; ++j) {
            h[j] = f2bf_rn(v[j]);
            s = fmaf(v[j], v[j], s);
            fcol[j] += v[j];
        }
        *(u16x8*)(xhi + base) = h;
#pragma unroll
        for (int off = 32; off; off >>= 1) s += __shfl_xor(s, off);
        if (lane == 0) sq[row] = s;
    }
#pragma unroll
    for (int j = 0; j < 8; ++j) colbuf[wave][lane * 8 + j] = fcol[j];
    __syncthreads();
    const int c = threadIdx.x * 2;
    float2 r;
    r.x = colbuf[0][c] + colbuf[1][c] + colbuf[2][c] + colbuf[3][c];
    r.y = colbuf[0][c + 1] + colbuf[1][c + 1] + colbuf[2][c + 1] + colbuf[3][c + 1];
    *(float2*)(colpart + (size_t)blockIdx.x * D_DIM + c) = r;
}

// Bandwidth from analytic sum; also weights + zeroing of loss accumulator.
__global__ __launch_bounds__(256) void k_bw(const float* __restrict__ sq,
                                            const float* __restrict__ colpart,
                                            const float* __restrict__ imw,
                                            const int* __restrict__ y,
                                            const int* __restrict__ alpha_p,
                                            float* __restrict__ w,
                                            float* __restrict__ invbw,
                                            double* __restrict__ accum,
                                            unsigned int* __restrict__ cnt) {
    const int tid = threadIdx.x;
    if (tid == 0) { accum[2] = 0.0; *cnt = 0u; }
    const float a = (float)alpha_p[0];
    for (int i = tid; i < N_SRC; i += 256) w[i] = a * imw[y[i]] + (1.0f - a);
    double s2 = 0.0;
    for (int i = tid; i < N_TOT; i += 256) s2 += (double)sq[i];
    double cs0 = 0.0, cs1 = 0.0;
    const int c = tid * 2;
#pragma unroll 8
    for (int b = 0; b < NPREP; ++b) {
        float2 v = *(const float2*)(colpart + (size_t)b * D_DIM + c);
        cs0 += (double)v.x;
        cs1 += (double)v.y;
    }
    double sc = cs0 * cs0 + cs1 * cs1;
    __shared__ double r1[256], r2[256];
    r1[tid] = s2; r2[tid] = sc;
    __syncthreads();
    for (int off = 128; off; off >>= 1) {
        if (tid < off) { r1[tid] += r1[tid + off]; r2[tid] += r2[tid + off]; }
        __syncthreads();
    }
    if (tid == 0) {
        // sum of clamped l2 == analytic sum (clamp only trims diagonal fp noise)
        double sum_l2 = 2.0 * (double)N_TOT * r1[0] - 2.0 * r2[0];
        double bw = sum_l2 / ((double)N_TOT * (double)N_TOT - (double)N_TOT);
        bw *= 0.25;  // / KERNEL_MUL^(KERNEL_NUM/2)
        double m = 1.0;
        for (int i = 0; i < 5; ++i) { invbw[i] = (float)(1.0 / (bw * m)); m *= 2.0; }
    }
}

// hi-only Gram, NO LDS: the 16x16x32 bf16 fragment layout (lane: row=lane&15,
// k=(lane>>4)*8..+7) maps each lane to a contiguous 16B global chunk of xhi,
// for BOTH operands (Gram: B-frag rows are xhi rows too). Fragments load
// straight global->VGPR; waves run barrier-free; L1/L2 serve the reuse.
__global__ __launch_bounds__(256) void k_pairs(const unsigned short* __restrict__ xhi,
                                               const float* __restrict__ sq,
                                               const float* __restrict__ w,
                                               const float* __restrict__ invbw,
                                               double* __restrict__ accum,
                                               unsigned int* __restrict__ cnt,
                                               float* __restrict__ out) {
    // XCD-chunked bijective remap (8 XCDs, 2080 % 8 == 0): consecutive bids on
    // one XCD share panels -> panels stay in that XCD's L2.
    int bid = (blockIdx.x & 7) * (NTILES / 8) + (blockIdx.x >> 3);
    int ti = 0, rem = bid;
    while (rem >= NT - ti) { rem -= NT - ti; ++ti; }
    const int tj = ti + rem;
    const int i0 = ti * BM, j0 = tj * BM;

    __shared__ double sdl4[4];

    const int tid = threadIdx.x;
    const int lane = tid & 63;
    const int wave = tid >> 6;
    const int wr = wave >> 1, wc = wave & 1;   // 2x2 wave quadrants, 64x64 each
    const int lr = lane & 15, lg = lane >> 4;  // frag row / k-chunk group

    f32x4 acc[4][4];
#pragma unroll
    for (int m = 0; m < 4; ++m)
#pragma unroll
        for (int n = 0; n < 4; ++n) acc[m][n] = f32x4{0.f, 0.f, 0.f, 0.f};

    // per-lane fragment base addresses (16B chunks, 16-row stride between frags)
    const unsigned short* aRow = xhi + (size_t)(i0 + wr * 64 + lr) * D_DIM + lg * 8;
    const unsigned short* bRow = xhi + (size_t)(j0 + wc * 64 + lr) * D_DIM + lg * 8;

    bf16x8 aA[4], bA[4], aB[4], bB[4];  // two named sets (rule #20: static idx)
#pragma unroll
    for (int m = 0; m < 4; ++m) {
        aA[m] = *(const bf16x8*)(aRow + m * 16 * D_DIM);
        bA[m] = *(const bf16x8*)(bRow + m * 16 * D_DIM);
    }
#pragma unroll
    for (int t = 0; t < 16; t += 2) {
        const int k1 = (t + 1) * 32;
#pragma unroll
        for (int m = 0; m < 4; ++m) {  // prefetch set B (step t+1)
            aB[m] = *(const bf16x8*)(aRow + m * 16 * D_DIM + k1);
            bB[m] = *(const bf16x8*)(bRow + m * 16 * D_DIM + k1);
        }
#pragma unroll
        for (int m = 0; m < 4; ++m)
#pragma unroll
            for (int n = 0; n < 4; ++n)
                acc[m][n] = __builtin_amdgcn_mfma_f32_16x16x32_bf16(aA[m], bA[n], acc[m][n], 0, 0, 0);
        if (t + 2 < 16) {
            const int k2 = (t + 2) * 32;
#pragma unroll
            for (int m = 0; m < 4; ++m) {  // prefetch set A (step t+2)
                aA[m] = *(const bf16x8*)(aRow + m * 16 * D_DIM + k2);
                bA[m] = *(const bf16x8*)(bRow + m * 16 * D_DIM + k2);
            }
        }
#pragma unroll
        for (int m = 0; m < 4; ++m)
#pragma unroll
            for (int n = 0; n < 4; ++n)
                acc[m][n] = __builtin_amdgcn_mfma_f32_16x16x32_bf16(aB[m], bB[n], acc[m][n], 0, 0, 0);
    }

    // ---- epilogue ----
    // C/D layout (m89-verified): col = lane&15 (B row), row = (lane>>4)*4 + reg
    float sqi[4][4], wi[4][4], sqj[4], wj[4];
#pragma unroll
    for (int m = 0; m < 4; ++m)
#pragma unroll
        for (int j = 0; j < 4; ++j) {
            int i = i0 + wr * 64 + m * 16 + lg * 4 + j;
            sqi[m][j] = sq[i];
            wi[m][j] = (i < N_SRC) ? w[i] : 0.f;
        }
#pragma unroll
    for (int n = 0; n < 4; ++n) {
        int jg = j0 + wc * 64 + n * 16 + lr;
        sqj[n] = sq[jg];
        wj[n] = (jg < N_SRC) ? w[jg] : 0.f;
    }
    // geometric bandwidths: with t = exp(-l2*ib4): k5 = t + t^2 + t^4 + t^8 + t^16
    const float nib4 = -invbw[4];

    const bool diag = (ti == tj);
    const int region = (tj < NT / 2) ? 0 : ((ti >= NT / 2) ? 1 : 2);  // 0=ss 1=tt 2=st

    float facc = 0.f;  // region uniform per block -> single fp32 accumulator
#pragma unroll
    for (int m = 0; m < 4; ++m)
#pragma unroll
        for (int n = 0; n < 4; ++n)
#pragma unroll
            for (int j = 0; j < 4; ++j) {
                int rg = wr * 64 + m * 16 + lg * 4 + j;
                int cg = wc * 64 + n * 16 + lr;
                if (diag && rg >= cg) continue;
                float l2 = fmaf(-2.f, acc[m][n][j], sqi[m][j] + sqj[n]);
                l2 = fmaxf(l2, 0.f);
                float t = __expf(l2 * nib4);
                float t2 = t * t, t4 = t2 * t2, t8 = t4 * t4, t16 = t8 * t8;
                float k5 = t + t2 + t4 + t8 + t16;
                float cf;
                if (region == 0)      cf = wi[m][j] * wj[n];
                else if (region == 1) cf = 1.f;
                else                  cf = wi[m][j];
                facc = fmaf(k5, cf, facc);
            }

    // wave shuffle-reduce, then 4-entry LDS combine, one atomic per block
#pragma unroll
    for (int off = 32; off; off >>= 1) facc += __shfl_xor(facc, off);
    if (lane == 0) sdl4[wave] = (double)facc;
    __syncthreads();
    if (tid == 0) {
        const double C_SS = 1.0 / 8386560.0;   // n_s*(n_s-1)/2 == n_t*(n_t-1)/2
        const double C_ST = 2.0 / 16777216.0;  // 2/(n_s*n_t)
        double scale = (region == 2) ? -C_ST : C_SS;
        atomicAdd(&accum[2], scale * (sdl4[0] + sdl4[1] + sdl4[2] + sdl4[3]));
        __threadfence();
        unsigned int old = atomicAdd(cnt, 1u);
        if (old == NTILES - 1) {
            double v = atomicAdd(&accum[2], 0.0);  // device-scope coherent read
            out[0] = (float)v;
        }
    }
}

extern "C" void kernel_launch(void* const* d_in, const int* in_sizes, int n_in,
                              void* d_out, int out_size, void* d_ws, size_t ws_size,
                              hipStream_t stream) {
    const float* x    = (const float*)d_in[0];
    const float* imw  = (const float*)d_in[1];
    const int*   y    = (const int*)d_in[3];
    const int*   alph = (const int*)d_in[4];
    float* out = (float*)d_out;

    char* ws = (char*)d_ws;
    double*       accum   = (double*)ws;
    unsigned int* cnt     = (unsigned int*)(ws + 64);
    float*        invbw   = (float*)(ws + 128);
    float*        sq      = (float*)(ws + 4096);
    float*        wgt     = (float*)(ws + 36864);
    float*        colpart = (float*)(ws + 53248);
    unsigned short* xhi   = (unsigned short*)(ws + 577536);

    k_prep<<<NPREP, 256, 0, stream>>>(x, xhi, sq, colpart);
    k_bw<<<1, 256, 0, stream>>>(sq, colpart, imw, y, alph, wgt, invbw, accum, cnt);
    k_pairs<<<NTILES, 256, 0, stream>>>(xhi, sq, wgt, invbw, accum, cnt, out);
}

// Round 9
// 188.645 us; speedup vs baseline: 1.5431x; 1.5431x over previous
//
#include <hip/hip_runtime.h>
#include <math.h>

#define N_TOT 8192
#define N_SRC 4096
#define D_DIM 512
#define BM2 256
#define NT2 (N_TOT / BM2)            /* 32 tiles per dim */
#define NTILES2 (NT2 * (NT2 + 1) / 2) /* 528; 528 % 8 == 0 */
#define NPREP 256

typedef short bf16x8 __attribute__((ext_vector_type(8)));
typedef unsigned short u16x8 __attribute__((ext_vector_type(8)));
typedef float f32x4 __attribute__((ext_vector_type(4)));

// ws layout (bytes):
//   0      : double accum[4]   {2=loss}
//   64     : unsigned int cnt
//   128    : float invbw[5]
//   4096   : float sq[8192]
//   36864  : float w[4096]
//   53248  : float colpart[256][512]
//   577536 : ushort xhi[8192*512]  (8 MB)

__device__ __forceinline__ unsigned short f2bf_rn(float v) {
    unsigned int u = __float_as_uint(v);
    unsigned int r = (u + 0x7FFFu + ((u >> 16) & 1u)) >> 16;
    return (unsigned short)r;
}

__global__ __launch_bounds__(256) void k_prep(const float* __restrict__ x,
                                              unsigned short* __restrict__ xhi,
                                              float* __restrict__ sq,
                                              float* __restrict__ colpart) {
    const int wave = threadIdx.x >> 6;
    const int lane = threadIdx.x & 63;
    __shared__ float colbuf[4][512];
    float fcol[8];
#pragma unroll
    for (int j = 0; j < 8; ++j) fcol[j] = 0.f;
#pragma unroll
    for (int r8 = 0; r8 < 8; ++r8) {
        const int row = blockIdx.x * 32 + wave * 8 + r8;
        const size_t base = (size_t)row * D_DIM + lane * 8;
        float v[8];
        *(float4*)&v[0] = *(const float4*)(x + base);
        *(float4*)&v[4] = *(const float4*)(x + base + 4);
        u16x8 h;
        float s = 0.f;
#pragma unroll
        for (int j = 0; j < 8; ++j) {
            h[j] = f2bf_rn(v[j]);
            s = fmaf(v[j], v[j], s);
            fcol[j] += v[j];
        }
        *(u16x8*)(xhi + base) = h;
#pragma unroll
        for (int off = 32; off; off >>= 1) s += __shfl_xor(s, off);
        if (lane == 0) sq[row] = s;
    }
#pragma unroll
    for (int j = 0; j < 8; ++j) colbuf[wave][lane * 8 + j] = fcol[j];
    __syncthreads();
    const int c = threadIdx.x * 2;
    float2 r;
    r.x = colbuf[0][c] + colbuf[1][c] + colbuf[2][c] + colbuf[3][c];
    r.y = colbuf[0][c + 1] + colbuf[1][c + 1] + colbuf[2][c + 1] + colbuf[3][c + 1];
    *(float2*)(colpart + (size_t)blockIdx.x * D_DIM + c) = r;
}

__global__ __launch_bounds__(256) void k_bw(const float* __restrict__ sq,
                                            const float* __restrict__ colpart,
                                            const float* __restrict__ imw,
                                            const int* __restrict__ y,
                                            const int* __restrict__ alpha_p,
                                            float* __restrict__ w,
                                            float* __restrict__ invbw,
                                            double* __restrict__ accum,
                                            unsigned int* __restrict__ cnt) {
    const int tid = threadIdx.x;
    if (tid == 0) { accum[2] = 0.0; *cnt = 0u; }
    const float a = (float)alpha_p[0];
    for (int i = tid; i < N_SRC; i += 256) w[i] = a * imw[y[i]] + (1.0f - a);
    double s2 = 0.0;
    for (int i = tid; i < N_TOT; i += 256) s2 += (double)sq[i];
    double cs0 = 0.0, cs1 = 0.0;
    const int c = tid * 2;
#pragma unroll 8
    for (int b = 0; b < NPREP; ++b) {
        float2 v = *(const float2*)(colpart + (size_t)b * D_DIM + c);
        cs0 += (double)v.x;
        cs1 += (double)v.y;
    }
    double sc = cs0 * cs0 + cs1 * cs1;
    __shared__ double r1[256], r2[256];
    r1[tid] = s2; r2[tid] = sc;
    __syncthreads();
    for (int off = 128; off; off >>= 1) {
        if (tid < off) { r1[tid] += r1[tid + off]; r2[tid] += r2[tid + off]; }
        __syncthreads();
    }
    if (tid == 0) {
        double sum_l2 = 2.0 * (double)N_TOT * r1[0] - 2.0 * sc * 0.0 - 2.0 * r2[0];
        double bw = sum_l2 / ((double)N_TOT * (double)N_TOT - (double)N_TOT);
        bw *= 0.25;
        double m = 1.0;
        for (int i = 0; i < 5; ++i) { invbw[i] = (float)(1.0 / (bw * m)); m *= 2.0; }
    }
}

__device__ __forceinline__ void gload_lds16(const unsigned short* g, char* l) {
    __builtin_amdgcn_global_load_lds((const __attribute__((address_space(1))) void*)g,
                                     (__attribute__((address_space(3))) void*)l,
                                     16, 0, 0);
}

// 256x256 8-phase Gram kernel (m201-template port).
// LDS per buf: A[256][64]bf16 (ht0 rows0-127 @0, ht1 @16K), B same @32K. 2 bufs.
// Swizzle: 16B-chunk index ^= (row&7) on both write-source and read.
__global__ __launch_bounds__(512, 2) void k_pairs(const unsigned short* __restrict__ xhi,
                                                  const float* __restrict__ sq,
                                                  const float* __restrict__ w,
                                                  const float* __restrict__ invbw,
                                                  double* __restrict__ accum,
                                                  unsigned int* __restrict__ cnt,
                                                  float* __restrict__ out) {
    int bid = (blockIdx.x & 7) * (NTILES2 / 8) + (blockIdx.x >> 3);
    int ti = 0, rem = bid;
    while (rem >= NT2 - ti) { rem -= NT2 - ti; ++ti; }
    const int tj = ti + rem;
    const int i0 = ti * BM2, j0 = tj * BM2;

    __shared__ __align__(16) char lds[2 * 65536];
    __shared__ double sdl8[8];

    const int tid = threadIdx.x;
    const int lane = tid & 63;
    const int wave = tid >> 6;
    const int wr = wave >> 2, wc = wave & 3;   // 2x4 waves; wave owns 128x64
    const int lr = lane & 15, lg = lane >> 4;

    // ds_read precomputed bases (byte offsets within a buffer)
    const int aBase = wr * 16384 + lr * 128;
    const int bBase = 32768 + (wc >> 1) * 16384 + (wc & 1) * 8192 + lr * 128;
    int cxor16[2];
    cxor16[0] = ((lg ^ (lr & 7)) << 4);
    cxor16[1] = (((4 + lg) ^ (lr & 7)) << 4);

    // stage precompute: thread tid stages rows (r*64 + tid>>3), phys chunk tid&7
    const int srow = tid >> 3;
    const int sc = (tid & 7) ^ (srow & 7);           // logical chunk (inverse swz)
    const unsigned short* aPanel = xhi + (size_t)i0 * D_DIM;
    const unsigned short* bPanel = xhi + (size_t)j0 * D_DIM;

    f32x4 acc[8][4];
#pragma unroll
    for (int m = 0; m < 8; ++m)
#pragma unroll
        for (int n = 0; n < 4; ++n) acc[m][n] = f32x4{0.f, 0.f, 0.f, 0.f};

    // STAGE one half-tile: panel P (0=A,1=B), half h, dbuf b, K-tile kt
#define STAGE_HT(P, h, b, kt)                                                          \
    do {                                                                               \
        const unsigned short* _p = (P) ? bPanel : aPanel;                              \
        char* _dst = lds + (b) * 65536 + (P) * 32768 + (h) * 16384 + tid * 16;         \
        _Pragma("unroll") for (int _r = 0; _r < 2; ++_r) {                             \
            gload_lds16(_p + (size_t)((h) * 128 + _r * 64 + srow) * D_DIM +            \
                            (kt) * 64 + sc * 8,                                        \
                        _dst + _r * 8192);                                             \
        }                                                                              \
    } while (0)

    // prologue: tile0 {A0,B0,B1,A1} then tile1 {B0,A0}; wait tile0 (leave 4)
    STAGE_HT(0, 0, 0, 0); STAGE_HT(1, 0, 0, 0); STAGE_HT(1, 1, 0, 0); STAGE_HT(0, 1, 0, 0);
    STAGE_HT(1, 0, 1, 1); STAGE_HT(0, 0, 1, 1);
    asm volatile("s_waitcnt vmcnt(4)" ::: "memory");
    __builtin_amdgcn_s_barrier();
    __builtin_amdgcn_sched_barrier(0);

    bf16x8 aR[4][2], bLo[2][2], bHi[2][2];

#define LD_A(Mq)                                                                       \
    _Pragma("unroll") for (int _m = 0; _m < 4; ++_m)                                   \
    _Pragma("unroll") for (int _k = 0; _k < 2; ++_k)                                   \
        aR[_m][_k] = *(const bf16x8*)(base + aBase + (Mq) * 8192 + _m * 2048 + cxor16[_k]);
#define LD_B(dstB, Nq)                                                                 \
    _Pragma("unroll") for (int _n = 0; _n < 2; ++_n)                                   \
    _Pragma("unroll") for (int _k = 0; _k < 2; ++_k)                                   \
        dstB[_n][_k] = *(const bf16x8*)(base + bBase + ((Nq) * 2 + _n) * 2048 + cxor16[_k]);
#define MFMA_Q(Mq, Nq, B)                                                              \
    __builtin_amdgcn_s_setprio(1);                                                     \
    _Pragma("unroll") for (int _m = 0; _m < 4; ++_m)                                   \
    _Pragma("unroll") for (int _n = 0; _n < 2; ++_n)                                   \
    _Pragma("unroll") for (int _k = 0; _k < 2; ++_k)                                   \
        acc[(Mq) * 4 + _m][(Nq) * 2 + _n] = __builtin_amdgcn_mfma_f32_16x16x32_bf16(   \
            aR[_m][_k], B[_n][_k], acc[(Mq) * 4 + _m][(Nq) * 2 + _n], 0, 0, 0);        \
    __builtin_amdgcn_s_setprio(0);
#define BAR1()                                                                         \
    __builtin_amdgcn_s_barrier();                                                      \
    asm volatile("s_waitcnt lgkmcnt(0)" ::: "memory");                                 \
    __builtin_amdgcn_sched_barrier(0);
#define BAR2()                                                                         \
    __builtin_amdgcn_s_barrier();                                                      \
    __builtin_amdgcn_sched_barrier(0);

    for (int t = 0; t < 8; ++t) {
        const char* base = lds + (t & 1) * 65536;
        const int bn = (t + 1) & 1;  // dbuf of tile t+1 (and t+2 = t&1)
        // ph0: read A-Mlo + B-Nlo; stage B1 of t+1
        LD_A(0); LD_B(bLo, 0);
        if (t < 7) STAGE_HT(1, 1, bn, t + 1);
        BAR1(); MFMA_Q(0, 0, bLo); BAR2();
        // ph1: read B-Nhi; stage A1 of t+1
        LD_B(bHi, 1);
        if (t < 7) STAGE_HT(0, 1, bn, t + 1);
        BAR1(); MFMA_Q(0, 1, bHi); BAR2();
        // ph2: read A-Mhi; stage B0 of t+2
        LD_A(1);
        if (t < 6) STAGE_HT(1, 0, t & 1, t + 2);
        BAR1(); MFMA_Q(1, 1, bHi); BAR2();
        // ph3: no ds_read (bLo kept); stage A0 of t+2; boundary vmcnt
        if (t < 6) STAGE_HT(0, 0, t & 1, t + 2);
        BAR1(); MFMA_Q(1, 0, bLo);
        if (t < 6) { asm volatile("s_waitcnt vmcnt(4)" ::: "memory"); }
        else if (t == 6) { asm volatile("s_waitcnt vmcnt(0)" ::: "memory"); }
        BAR2();
    }
#undef STAGE_HT
#undef LD_A
#undef LD_B
#undef MFMA_Q
#undef BAR1
#undef BAR2

    // ---- epilogue ----
    const float nib4 = -invbw[4];
    const bool diag = (ti == tj);
    const int region = (tj < NT2 / 2) ? 0 : ((ti >= NT2 / 2) ? 1 : 2);  // ss/tt/st

    float sqj[4], wj[4];
#pragma unroll
    for (int n = 0; n < 4; ++n) {
        int jg = j0 + wc * 64 + n * 16 + lr;
        sqj[n] = sq[jg];
        wj[n] = (jg < N_SRC) ? w[jg] : 0.f;
    }
    float facc = 0.f;
#pragma unroll
    for (int m = 0; m < 8; ++m)
#pragma unroll
        for (int jj = 0; jj < 4; ++jj) {
            const int rg = wr * 128 + m * 16 + lg * 4 + jj;
            const int i = i0 + rg;
            const float sqi = sq[i];
            const float wi = (i < N_SRC) ? w[i] : 0.f;
#pragma unroll
            for (int n = 0; n < 4; ++n) {
                const int cg = wc * 64 + n * 16 + lr;
                if (diag && rg >= cg) continue;
                float l2 = fmaf(-2.f, acc[m][n][jj], sqi + sqj[n]);
                l2 = fmaxf(l2, 0.f);
                float tt = __expf(l2 * nib4);
                float t2 = tt * tt, t4 = t2 * t2, t8 = t4 * t4, t16 = t8 * t8;
                float k5 = tt + t2 + t4 + t8 + t16;
                float cf;
                if (region == 0)      cf = wi * wj[n];
                else if (region == 1) cf = 1.f;
                else                  cf = wi;
                facc = fmaf(k5, cf, facc);
            }
        }

#pragma unroll
    for (int off = 32; off; off >>= 1) facc += __shfl_xor(facc, off);
    if (lane == 0) sdl8[wave] = (double)facc;
    __syncthreads();
    if (tid == 0) {
        const double C_SS = 1.0 / 8386560.0;
        const double C_ST = 2.0 / 16777216.0;
        double s = 0.0;
#pragma unroll
        for (int q = 0; q < 8; ++q) s += sdl8[q];
        double scale = (region == 2) ? -C_ST : C_SS;
        atomicAdd(&accum[2], scale * s);
        __threadfence();
        unsigned int old = atomicAdd(cnt, 1u);
        if (old == NTILES2 - 1) {
            double v = atomicAdd(&accum[2], 0.0);
            out[0] = (float)v;
        }
    }
}

extern "C" void kernel_launch(void* const* d_in, const int* in_sizes, int n_in,
                              void* d_out, int out_size, void* d_ws, size_t ws_size,
                              hipStream_t stream) {
    const float* x    = (const float*)d_in[0];
    const float* imw  = (const float*)d_in[1];
    const int*   y    = (const int*)d_in[3];
    const int*   alph = (const int*)d_in[4];
    float* out = (float*)d_out;

    char* ws = (char*)d_ws;
    double*       accum   = (double*)ws;
    unsigned int* cnt     = (unsigned int*)(ws + 64);
    float*        invbw   = (float*)(ws + 128);
    float*        sq      = (float*)(ws + 4096);
    float*        wgt     = (float*)(ws + 36864);
    float*        colpart = (float*)(ws + 53248);
    unsigned short* xhi   = (unsigned short*)(ws + 577536);

    k_prep<<<NPREP, 256, 0, stream>>>(x, xhi, sq, colpart);
    k_bw<<<1, 256, 0, stream>>>(sq, colpart, imw, y, alph, wgt, invbw, accum, cnt);
    k_pairs<<<NTILES2, 512, 0, stream>>>(xhi, sq, wgt, invbw, accum, cnt, out);
}

// Round 10
// 186.792 us; speedup vs baseline: 1.5584x; 1.0099x over previous
//
#include <hip/hip_runtime.h>
#include <math.h>

#define N_TOT 8192
#define N_SRC 4096
#define D_DIM 512
#define BM2 256
#define NT2 (N_TOT / BM2)             /* 32 tiles per dim */
#define NTILES2 (NT2 * (NT2 + 1) / 2) /* 528; 528 % 8 == 0 */
#define NPREP 256

typedef short bf16x8 __attribute__((ext_vector_type(8)));
typedef unsigned short u16x8 __attribute__((ext_vector_type(8)));
typedef float f32x4 __attribute__((ext_vector_type(4)));

// ws layout (bytes):
//   0      : double accum[4]   {2=loss}
//   64     : unsigned int cnt
//   128    : float invbw[5]
//   4096   : double colsum[512]  (4 KB, pre-zeroed via memsetAsync)
//   8192   : float sq[8192]      (32 KB)
//   40960  : float w[4096]       (16 KB)
//   65536  : ushort xhi[8192*512] (8 MB)

__device__ __forceinline__ unsigned short f2bf_rn(float v) {
    unsigned int u = __float_as_uint(v);
    unsigned int r = (u + 0x7FFFu + ((u >> 16) & 1u)) >> 16;
    return (unsigned short)r;
}

// One pass over x: bf16 round + row sum-of-squares + column sums (f64 atomics).
__global__ __launch_bounds__(256) void k_prep(const float* __restrict__ x,
                                              unsigned short* __restrict__ xhi,
                                              float* __restrict__ sq,
                                              double* __restrict__ colsum) {
    const int wave = threadIdx.x >> 6;
    const int lane = threadIdx.x & 63;
    __shared__ float colbuf[4][512];
    float fcol[8];
#pragma unroll
    for (int j = 0; j < 8; ++j) fcol[j] = 0.f;
#pragma unroll
    for (int r8 = 0; r8 < 8; ++r8) {
        const int row = blockIdx.x * 32 + wave * 8 + r8;
        const size_t base = (size_t)row * D_DIM + lane * 8;
        float v[8];
        *(float4*)&v[0] = *(const float4*)(x + base);
        *(float4*)&v[4] = *(const float4*)(x + base + 4);
        u16x8 h;
        float s = 0.f;
#pragma unroll
        for (int j = 0; j < 8; ++j) {
            h[j] = f2bf_rn(v[j]);
            s = fmaf(v[j], v[j], s);
            fcol[j] += v[j];
        }
        *(u16x8*)(xhi + base) = h;
#pragma unroll
        for (int off = 32; off; off >>= 1) s += __shfl_xor(s, off);
        if (lane == 0) sq[row] = s;
    }
#pragma unroll
    for (int j = 0; j < 8; ++j) colbuf[wave][lane * 8 + j] = fcol[j];
    __syncthreads();
    const int c = threadIdx.x * 2;
    double s0 = (double)(colbuf[0][c] + colbuf[1][c]) + (double)(colbuf[2][c] + colbuf[3][c]);
    double s1 = (double)(colbuf[0][c + 1] + colbuf[1][c + 1]) + (double)(colbuf[2][c + 1] + colbuf[3][c + 1]);
    atomicAdd(&colsum[c], s0);
    atomicAdd(&colsum[c + 1], s1);
}

// Bandwidth from analytic sum; also weights + zeroing of loss accumulator.
__global__ __launch_bounds__(256) void k_bw(const float* __restrict__ sq,
                                            const double* __restrict__ colsum,
                                            const float* __restrict__ imw,
                                            const int* __restrict__ y,
                                            const int* __restrict__ alpha_p,
                                            float* __restrict__ w,
                                            float* __restrict__ invbw,
                                            double* __restrict__ accum,
                                            unsigned int* __restrict__ cnt) {
    const int tid = threadIdx.x;
    if (tid == 0) { accum[2] = 0.0; *cnt = 0u; }
    const float a = (float)alpha_p[0];
    for (int i = tid; i < N_SRC; i += 256) w[i] = a * imw[y[i]] + (1.0f - a);
    double s2 = 0.0;
    for (int i = tid; i < N_TOT; i += 256) s2 += (double)sq[i];
    double sc = 0.0;
    for (int c = tid; c < D_DIM; c += 256) {
        double v = colsum[c];
        sc += v * v;
    }
    __shared__ double r1[256], r2[256];
    r1[tid] = s2; r2[tid] = sc;
    __syncthreads();
    for (int off = 128; off; off >>= 1) {
        if (tid < off) { r1[tid] += r1[tid + off]; r2[tid] += r2[tid + off]; }
        __syncthreads();
    }
    if (tid == 0) {
        // sum of clamped l2 == analytic sum (clamp only trims diagonal fp noise)
        double sum_l2 = 2.0 * (double)N_TOT * r1[0] - 2.0 * r2[0];
        double bw = sum_l2 / ((double)N_TOT * (double)N_TOT - (double)N_TOT);
        bw *= 0.25;  // / KERNEL_MUL^(KERNEL_NUM/2)
        double m = 1.0;
        for (int i = 0; i < 5; ++i) { invbw[i] = (float)(1.0 / (bw * m)); m *= 2.0; }
    }
}

__device__ __forceinline__ void gload_lds16(const unsigned short* g, char* l) {
    __builtin_amdgcn_global_load_lds((const __attribute__((address_space(1))) void*)g,
                                     (__attribute__((address_space(3))) void*)l,
                                     16, 0, 0);
}

// 256x256 8-phase Gram kernel. R9 geometry frozen; scheduler UNPINNED:
// no sched_barrier(0), no blanket lgkmcnt(0) (compiler emits precise counted
// waits for its own ds_reads - G7/m97). Raw s_barrier with memory clobber
// orders LDS ops without draining vmcnt; counted vmcnt only at boundaries.
__global__ __launch_bounds__(512, 2) void k_pairs(const unsigned short* __restrict__ xhi,
                                                  const float* __restrict__ sq,
                                                  const float* __restrict__ w,
                                                  const float* __restrict__ invbw,
                                                  double* __restrict__ accum,
                                                  unsigned int* __restrict__ cnt,
                                                  float* __restrict__ out) {
    int bid = (blockIdx.x & 7) * (NTILES2 / 8) + (blockIdx.x >> 3);
    int ti = 0, rem = bid;
    while (rem >= NT2 - ti) { rem -= NT2 - ti; ++ti; }
    const int tj = ti + rem;
    const int i0 = ti * BM2, j0 = tj * BM2;

    __shared__ __align__(16) char lds[2 * 65536];
    __shared__ double sdl8[8];

    const int tid = threadIdx.x;
    const int lane = tid & 63;
    const int wave = tid >> 6;
    const int wr = wave >> 2, wc = wave & 3;   // 2x4 waves; wave owns 128x64
    const int lr = lane & 15, lg = lane >> 4;

    const int aBase = wr * 16384 + lr * 128;
    const int bBase = 32768 + (wc >> 1) * 16384 + (wc & 1) * 8192 + lr * 128;
    int cxor16[2];
    cxor16[0] = ((lg ^ (lr & 7)) << 4);
    cxor16[1] = (((4 + lg) ^ (lr & 7)) << 4);

    const int srow = tid >> 3;
    const int sc = (tid & 7) ^ (srow & 7);  // logical chunk (inverse swizzle)
    const unsigned short* aPanel = xhi + (size_t)i0 * D_DIM;
    const unsigned short* bPanel = xhi + (size_t)j0 * D_DIM;

    f32x4 acc[8][4];
#pragma unroll
    for (int m = 0; m < 8; ++m)
#pragma unroll
        for (int n = 0; n < 4; ++n) acc[m][n] = f32x4{0.f, 0.f, 0.f, 0.f};

#define STAGE_HT(P, h, b, kt)                                                          \
    do {                                                                               \
        const unsigned short* _p = (P) ? bPanel : aPanel;                              \
        char* _dst = lds + (b) * 65536 + (P) * 32768 + (h) * 16384 + tid * 16;         \
        _Pragma("unroll") for (int _r = 0; _r < 2; ++_r) {                             \
            gload_lds16(_p + (size_t)((h) * 128 + _r * 64 + srow) * D_DIM +            \
                            (kt) * 64 + sc * 8,                                        \
                        _dst + _r * 8192);                                             \
        }                                                                              \
    } while (0)

    // prologue: tile0 {A0,B0,B1,A1}, tile1 {B0,A0}; wait tile0 (leave 4 in flight)
    STAGE_HT(0, 0, 0, 0); STAGE_HT(1, 0, 0, 0); STAGE_HT(1, 1, 0, 0); STAGE_HT(0, 1, 0, 0);
    STAGE_HT(1, 0, 1, 1); STAGE_HT(0, 0, 1, 1);
    asm volatile("s_waitcnt vmcnt(4)\n\ts_barrier" ::: "memory");

    bf16x8 aR[4][2], bLo[2][2], bHi[2][2];

#define LD_A(Mq)                                                                       \
    _Pragma("unroll") for (int _m = 0; _m < 4; ++_m)                                   \
    _Pragma("unroll") for (int _k = 0; _k < 2; ++_k)                                   \
        aR[_m][_k] = *(const bf16x8*)(base + aBase + (Mq) * 8192 + _m * 2048 + cxor16[_k]);
#define LD_B(dstB, Nq)                                                                 \
    _Pragma("unroll") for (int _n = 0; _n < 2; ++_n)                                   \
    _Pragma("unroll") for (int _k = 0; _k < 2; ++_k)                                   \
        dstB[_n][_k] = *(const bf16x8*)(base + bBase + ((Nq) * 2 + _n) * 2048 + cxor16[_k]);
#define MFMA_Q(Mq, Nq, B)                                                              \
    __builtin_amdgcn_s_setprio(1);                                                     \
    _Pragma("unroll") for (int _m = 0; _m < 4; ++_m)                                   \
    _Pragma("unroll") for (int _n = 0; _n < 2; ++_n)                                   \
    _Pragma("unroll") for (int _k = 0; _k < 2; ++_k)                                   \
        acc[(Mq) * 4 + _m][(Nq) * 2 + _n] = __builtin_amdgcn_mfma_f32_16x16x32_bf16(   \
            aR[_m][_k], B[_n][_k], acc[(Mq) * 4 + _m][(Nq) * 2 + _n], 0, 0, 0);        \
    __builtin_amdgcn_s_setprio(0);
#define BARRIER() asm volatile("s_barrier" ::: "memory")

    for (int t = 0; t < 8; ++t) {
        const char* base = lds + (t & 1) * 65536;
        const int bn = (t + 1) & 1;
        // ph0: stage B1(t+1); read A-Mlo + B-Nlo
        if (t < 7) STAGE_HT(1, 1, bn, t + 1);
        LD_A(0); LD_B(bLo, 0);
        BARRIER(); MFMA_Q(0, 0, bLo); BARRIER();
        // ph1: stage A1(t+1); read B-Nhi
        if (t < 7) STAGE_HT(0, 1, bn, t + 1);
        LD_B(bHi, 1);
        BARRIER(); MFMA_Q(0, 1, bHi); BARRIER();
        // ph2: stage B0(t+2); read A-Mhi
        if (t < 6) STAGE_HT(1, 0, t & 1, t + 2);
        LD_A(1);
        BARRIER(); MFMA_Q(1, 1, bHi); BARRIER();
        // ph3: stage A0(t+2); no ds_read (bLo kept); boundary counted vmcnt
        if (t < 6) STAGE_HT(0, 0, t & 1, t + 2);
        BARRIER(); MFMA_Q(1, 0, bLo);
        if (t < 6) { asm volatile("s_waitcnt vmcnt(4)" ::: "memory"); }
        else if (t == 6) { asm volatile("s_waitcnt vmcnt(0)" ::: "memory"); }
        BARRIER();
    }
#undef STAGE_HT
#undef LD_A
#undef LD_B
#undef MFMA_Q
#undef BARRIER

    // ---- epilogue ----
    const float nib4 = -invbw[4];
    const bool diag = (ti == tj);
    const int region = (tj < NT2 / 2) ? 0 : ((ti >= NT2 / 2) ? 1 : 2);  // ss/tt/st

    float sqj[4], wj[4];
#pragma unroll
    for (int n = 0; n < 4; ++n) {
        int jg = j0 + wc * 64 + n * 16 + lr;
        sqj[n] = sq[jg];
        wj[n] = (jg < N_SRC) ? w[jg] : 0.f;
    }
    float facc = 0.f;
#pragma unroll
    for (int m = 0; m < 8; ++m)
#pragma unroll
        for (int jj = 0; jj < 4; ++jj) {
            const int rg = wr * 128 + m * 16 + lg * 4 + jj;
            const int i = i0 + rg;
            const float sqi = sq[i];
            const float wi = (i < N_SRC) ? w[i] : 0.f;
#pragma unroll
            for (int n = 0; n < 4; ++n) {
                const int cg = wc * 64 + n * 16 + lr;
                if (diag && rg >= cg) continue;
                float l2 = fmaf(-2.f, acc[m][n][jj], sqi + sqj[n]);
                l2 = fmaxf(l2, 0.f);
                float tt = __expf(l2 * nib4);
                float t2 = tt * tt, t4 = t2 * t2, t8 = t4 * t4, t16 = t8 * t8;
                float k5 = tt + t2 + t4 + t8 + t16;
                float cf;
                if (region == 0)      cf = wi * wj[n];
                else if (region == 1) cf = 1.f;
                else                  cf = wi;
                facc = fmaf(k5, cf, facc);
            }
        }

#pragma unroll
    for (int off = 32; off; off >>= 1) facc += __shfl_xor(facc, off);
    if (lane == 0) sdl8[wave] = (double)facc;
    __syncthreads();
    if (tid == 0) {
        const double C_SS = 1.0 / 8386560.0;
        const double C_ST = 2.0 / 16777216.0;
        double s = 0.0;
#pragma unroll
        for (int q = 0; q < 8; ++q) s += sdl8[q];
        double scale = (region == 2) ? -C_ST : C_SS;
        atomicAdd(&accum[2], scale * s);
        __threadfence();
        unsigned int old = atomicAdd(cnt, 1u);
        if (old == NTILES2 - 1) {
            double v = atomicAdd(&accum[2], 0.0);
            out[0] = (float)v;
        }
    }
}

extern "C" void kernel_launch(void* const* d_in, const int* in_sizes, int n_in,
                              void* d_out, int out_size, void* d_ws, size_t ws_size,
                              hipStream_t stream) {
    const float* x    = (const float*)d_in[0];
    const float* imw  = (const float*)d_in[1];
    const int*   y    = (const int*)d_in[3];
    const int*   alph = (const int*)d_in[4];
    float* out = (float*)d_out;

    char* ws = (char*)d_ws;
    double*       accum  = (double*)ws;
    unsigned int* cnt    = (unsigned int*)(ws + 64);
    float*        invbw  = (float*)(ws + 128);
    double*       colsum = (double*)(ws + 4096);
    float*        sq     = (float*)(ws + 8192);
    float*        wgt    = (float*)(ws + 40960);
    unsigned short* xhi  = (unsigned short*)(ws + 65536);

    hipMemsetAsync(ws + 4096, 0, 4096, stream);  // colsum
    k_prep<<<NPREP, 256, 0, stream>>>(x, xhi, sq, colsum);
    k_bw<<<1, 256, 0, stream>>>(sq, colsum, imw, y, alph, wgt, invbw, accum, cnt);
    k_pairs<<<NTILES2, 512, 0, stream>>>(xhi, sq, wgt, invbw, accum, cnt, out);
}